// Round 1
// baseline (407.258 us; speedup 1.0000x reference)
//
#include <hip/hip_runtime.h>
#include <hip/hip_bf16.h>

typedef unsigned short u16;
typedef __attribute__((ext_vector_type(4))) float f32x4;
typedef __attribute__((ext_vector_type(8))) short s16x8;
typedef __attribute__((ext_vector_type(4))) unsigned short u16x4;

#define LOG2E 1.44269504088896f

__device__ inline u16 f2bf(float f) {
  union { float f; unsigned u; } x; x.f = f;
  unsigned r = x.u + 0x7FFFu + ((x.u >> 16) & 1u);
  return (u16)(r >> 16);
}

// ---------------- fp32 -> bf16 convert ----------------
__global__ void cvt_bf16(const float* __restrict__ src, u16* __restrict__ dst, int n4) {
  int i = blockIdx.x * blockDim.x + threadIdx.x;
  if (i < n4) {
    const float4 v = ((const float4*)src)[i];
    u16x4 o;
    o[0] = f2bf(v.x); o[1] = f2bf(v.y); o[2] = f2bf(v.z); o[3] = f2bf(v.w);
    ((u16x4*)dst)[i] = o;
  }
}

// ---------------- NT GEMM: C[m,n] = sum_k A[m,k]*B[n,k] + bias[n] ----------------
// 128x128 tile, BK=64, 4 waves (2x2 of 64x64), global_load_lds staging (m97 structure).
template<int STORE_BF16, int QKV_SCALE>
__global__ __launch_bounds__(256) void gemm_nt(
    const u16* __restrict__ A, const u16* __restrict__ B,
    const float* __restrict__ bias, void* __restrict__ C,
    int M, int N, int K)
{
  __shared__ u16 lsA[128 * 64];
  __shared__ u16 lsB[128 * 64];
  const int tid = threadIdx.x;
  const int wave = tid >> 6, lane = tid & 63;
  const int tm = blockIdx.y * 128, tn = blockIdx.x * 128;
  const int wr = wave >> 1, wc = wave & 1;
  const int lrow = lane >> 3, lcol = (lane & 7) * 8;
  const int il = lane & 15, g = lane >> 4;

  f32x4 acc[4][4] = {};

  for (int k0 = 0; k0 < K; k0 += 64) {
#pragma unroll
    for (int i = 0; i < 4; ++i) {
      int c = wave * 4 + i;
      const u16* ga = A + (size_t)(tm + c * 8 + lrow) * K + k0 + lcol;
      __builtin_amdgcn_global_load_lds((const __attribute__((address_space(1))) void*)ga,
                                       (__attribute__((address_space(3))) void*)&lsA[c * 512],
                                       16, 0, 0);
    }
#pragma unroll
    for (int i = 0; i < 4; ++i) {
      int c = wave * 4 + i;
      const u16* gb = B + (size_t)(tn + c * 8 + lrow) * K + k0 + lcol;
      __builtin_amdgcn_global_load_lds((const __attribute__((address_space(1))) void*)gb,
                                       (__attribute__((address_space(3))) void*)&lsB[c * 512],
                                       16, 0, 0);
    }
    __syncthreads();  // drains vmcnt before barrier (compiler-enforced)

#pragma unroll
    for (int kk = 0; kk < 2; ++kk) {
      s16x8 af[4], bfr[4];
#pragma unroll
      for (int i = 0; i < 4; ++i)
        af[i] = *(const s16x8*)&lsA[(wr * 64 + i * 16 + il) * 64 + kk * 32 + g * 8];
#pragma unroll
      for (int j = 0; j < 4; ++j)
        bfr[j] = *(const s16x8*)&lsB[(wc * 64 + j * 16 + il) * 64 + kk * 32 + g * 8];
#pragma unroll
      for (int i = 0; i < 4; ++i)
#pragma unroll
        for (int j = 0; j < 4; ++j)
          acc[i][j] = __builtin_amdgcn_mfma_f32_16x16x32_bf16(af[i], bfr[j], acc[i][j], 0, 0, 0);
    }
    __syncthreads();
  }

  // epilogue: C/D layout col=lane&15, row=(lane>>4)*4+r
#pragma unroll
  for (int i = 0; i < 4; ++i) {
    const int row0 = tm + wr * 64 + i * 16 + g * 4;
#pragma unroll
    for (int j = 0; j < 4; ++j) {
      const int col = tn + wc * 64 + j * 16 + il;
      const float bb = bias[col];
#pragma unroll
      for (int r = 0; r < 4; ++r) {
        float v = acc[i][j][r] + bb;
        if (QKV_SCALE) { if (col < 768) v *= 0.125f; }  // fold 1/sqrt(64) into Q
        if (STORE_BF16) ((u16*)C)[(size_t)(row0 + r) * N + col] = f2bf(v);
        else            ((float*)C)[(size_t)(row0 + r) * N + col] = v;
      }
    }
  }
}

// ---------------- flash attention ----------------
// grid: 3072 1-D; block 256 (4 waves). Each WG: one (b,h), 64 q-rows (16/wave).
// KV chunk = 64. K in LDS [k][e] stride 72 (pad kills the 128B-stride bank conflict),
// V transposed [e][k] stride 72, P per-wave [16][72].
__global__ __launch_bounds__(256) void attn_fwd(const u16* __restrict__ qkv,
                                               u16* __restrict__ concat)
{
  __shared__ u16 Kt[64 * 72];
  __shared__ u16 Vt[64 * 72];
  __shared__ u16 Pl[4][16 * 72];

  const int tid = threadIdx.x, wave = tid >> 6, lane = tid & 63;
  const int wg = blockIdx.x;
  // XCD co-location: all 16 q-blocks of a bh share (dispatch_idx % 8)
  const int bh = (wg & 7) + (wg >> 7) * 8;
  const int qb = (wg >> 3) & 15;
  const int b = bh / 12, h = bh % 12;

  const size_t rowbase = (size_t)b * 1024 * 2304;
  const int g = lane >> 4, il = lane & 15;
  const int qs0 = qb * 64 + wave * 16;

  // Q fragments (A-operand: lane holds q[lane&15][(lane>>4)*8+j]); scale pre-folded
  s16x8 qf[2];
  {
    const u16* qp = qkv + rowbase + (size_t)(qs0 + il) * 2304 + h * 64;
#pragma unroll
    for (int kk = 0; kk < 2; ++kk)
      qf[kk] = *(const s16x8*)(qp + kk * 32 + g * 8);
  }

  float mrow[4], lsum[4];
  f32x4 accO[4] = {};
#pragma unroll
  for (int r = 0; r < 4; ++r) { mrow[r] = -1e30f; lsum[r] = 0.f; }

  const int se8 = tid & 7;   // which 8-wide e group
  const int sk = tid >> 3;   // k row (0..31), +32 on second pass

  for (int kv0 = 0; kv0 < 1024; kv0 += 64) {
    // ---- stage K (row-major, pad 72) and V (transposed, pad 72) ----
#pragma unroll
    for (int p = 0; p < 2; ++p) {
      const int krow = sk + p * 32;
      const u16* kp = qkv + rowbase + (size_t)(kv0 + krow) * 2304 + 768 + h * 64 + se8 * 8;
      s16x8 kv_ = *(const s16x8*)kp;
      s16x8 vv_ = *(const s16x8*)(kp + 768);
      *(s16x8*)&Kt[krow * 72 + se8 * 8] = kv_;
#pragma unroll
      for (int j = 0; j < 8; ++j)
        Vt[(se8 * 8 + j) * 72 + krow] = (u16)vv_[j];
    }
    __syncthreads();

    // ---- scores: S[16q x 64k] as 4 col-frags ----
    f32x4 s[4] = {};
#pragma unroll
    for (int j = 0; j < 4; ++j)
#pragma unroll
      for (int kk = 0; kk < 2; ++kk) {
        s16x8 kf = *(const s16x8*)&Kt[(j * 16 + il) * 72 + kk * 32 + g * 8];
        s[j] = __builtin_amdgcn_mfma_f32_16x16x32_bf16(qf[kk], kf, s[j], 0, 0, 0);
      }

    // ---- online softmax (each 16-lane group owns 4 q-rows) ----
    float p4[4][4];
#pragma unroll
    for (int r = 0; r < 4; ++r) {
      float cm = fmaxf(fmaxf(s[0][r], s[1][r]), fmaxf(s[2][r], s[3][r]));
#pragma unroll
      for (int off = 1; off < 16; off <<= 1)
        cm = fmaxf(cm, __shfl_xor(cm, off));
      const float nm = fmaxf(mrow[r], cm);
      const float sc = exp2f((mrow[r] - nm) * LOG2E);
      float cs = 0.f;
#pragma unroll
      for (int j = 0; j < 4; ++j) {
        const float pv = exp2f((s[j][r] - nm) * LOG2E);
        p4[j][r] = pv; cs += pv;
      }
#pragma unroll
      for (int off = 1; off < 16; off <<= 1)
        cs += __shfl_xor(cs, off);
      lsum[r] = lsum[r] * sc + cs;
      mrow[r] = nm;
#pragma unroll
      for (int jj = 0; jj < 4; ++jj) accO[jj][r] *= sc;
    }

    // ---- P: C-layout -> LDS -> A-layout (wave-private, no barrier needed) ----
#pragma unroll
    for (int j = 0; j < 4; ++j)
#pragma unroll
      for (int r = 0; r < 4; ++r)
        Pl[wave][(g * 4 + r) * 72 + j * 16 + il] = f2bf(p4[j][r]);

    // ---- PV: O[16q x 64e] += P * V ----
#pragma unroll
    for (int kk = 0; kk < 2; ++kk) {
      s16x8 pa = *(const s16x8*)&Pl[wave][il * 72 + kk * 32 + g * 8];
#pragma unroll
      for (int jj = 0; jj < 4; ++jj) {
        s16x8 vf = *(const s16x8*)&Vt[(jj * 16 + il) * 72 + kk * 32 + g * 8];
        accO[jj] = __builtin_amdgcn_mfma_f32_16x16x32_bf16(pa, vf, accO[jj], 0, 0, 0);
      }
    }
    __syncthreads();
  }

  // ---- epilogue: O /= l, store concat[b*1024+s][h*64+e] ----
  const size_t orow = (size_t)b * 1024 + qs0;
#pragma unroll
  for (int jj = 0; jj < 4; ++jj) {
    const int col = h * 64 + jj * 16 + il;
#pragma unroll
    for (int r = 0; r < 4; ++r) {
      const float o = accO[jj][r] / lsum[r];
      concat[(orow + g * 4 + r) * 768 + col] = f2bf(o);
    }
  }
}

// ---------------- launch ----------------
extern "C" void kernel_launch(void* const* d_in, const int* in_sizes, int n_in,
                              void* d_out, int out_size, void* d_ws, size_t ws_size,
                              hipStream_t stream) {
  const float* x  = (const float*)d_in[0];
  const float* Wq = (const float*)d_in[1];
  const float* bq = (const float*)d_in[2];
  const float* Wk = (const float*)d_in[3];
  const float* bk = (const float*)d_in[4];
  const float* Wv = (const float*)d_in[5];
  const float* bv = (const float*)d_in[6];
  const float* Wo = (const float*)d_in[7];
  const float* bo = (const float*)d_in[8];

  const size_t XN = (size_t)16384 * 768;   // x / concat elems
  const size_t WN = (size_t)768 * 768;     // one weight matrix elems

  u16* xb   = (u16*)d_ws;                  // [16384,768] bf16
  u16* wqkv = xb + XN;                     // [2304,768] bf16 (Wq;Wk;Wv rows)
  u16* wo   = wqkv + 3 * WN;               // [768,768] bf16
  float* bqkv = (float*)(wo + WN);         // [2304] fp32
  u16* qkv  = (u16*)(bqkv + 2304);         // [16384,2304] bf16
  u16* cc   = xb;                          // concat aliases xb (xb dead after QKV GEMM)

  cvt_bf16<<<(int)(XN / 4 + 255) / 256, 256, 0, stream>>>(x, xb, (int)(XN / 4));
  cvt_bf16<<<(int)(WN / 4 + 255) / 256, 256, 0, stream>>>(Wq, wqkv, (int)(WN / 4));
  cvt_bf16<<<(int)(WN / 4 + 255) / 256, 256, 0, stream>>>(Wk, wqkv + WN, (int)(WN / 4));
  cvt_bf16<<<(int)(WN / 4 + 255) / 256, 256, 0, stream>>>(Wv, wqkv + 2 * WN, (int)(WN / 4));
  cvt_bf16<<<(int)(WN / 4 + 255) / 256, 256, 0, stream>>>(Wo, wo, (int)(WN / 4));
  hipMemcpyAsync(bqkv,        bq, 768 * sizeof(float), hipMemcpyDeviceToDevice, stream);
  hipMemcpyAsync(bqkv + 768,  bk, 768 * sizeof(float), hipMemcpyDeviceToDevice, stream);
  hipMemcpyAsync(bqkv + 1536, bv, 768 * sizeof(float), hipMemcpyDeviceToDevice, stream);

  gemm_nt<1, 1><<<dim3(2304 / 128, 16384 / 128), 256, 0, stream>>>(
      xb, wqkv, bqkv, qkv, 16384, 2304, 768);

  attn_fwd<<<3072, 256, 0, stream>>>(qkv, cc);

  gemm_nt<0, 0><<<dim3(768 / 128, 16384 / 128), 256, 0, stream>>>(
      cc, wo, bo, d_out, 16384, 768, 768);
}

// Round 2
// 298.622 us; speedup vs baseline: 1.3638x; 1.3638x over previous
//
#include <hip/hip_runtime.h>
#include <hip/hip_bf16.h>

typedef unsigned short u16;
typedef __attribute__((ext_vector_type(4))) float f32x4;
typedef __attribute__((ext_vector_type(8))) short s16x8;
typedef __attribute__((ext_vector_type(4))) unsigned short u16x4;
typedef __attribute__((ext_vector_type(8))) unsigned short u16x8;

#define LOG2E 1.44269504088896f

__device__ inline u16 f2bf(float f) {
  union { float f; unsigned u; } x; x.f = f;
  unsigned r = x.u + 0x7FFFu + ((x.u >> 16) & 1u);
  return (u16)(r >> 16);
}

// ---------------- fp32 -> bf16 convert ----------------
__global__ void cvt_bf16(const float* __restrict__ src, u16* __restrict__ dst, int n4) {
  int i = blockIdx.x * blockDim.x + threadIdx.x;
  if (i < n4) {
    const float4 v = ((const float4*)src)[i];
    u16x4 o;
    o[0] = f2bf(v.x); o[1] = f2bf(v.y); o[2] = f2bf(v.z); o[3] = f2bf(v.w);
    ((u16x4*)dst)[i] = o;
  }
}

// ---------------- NT GEMM (unchanged, verified round 1) ----------------
template<int STORE_BF16, int QKV_SCALE>
__global__ __launch_bounds__(256) void gemm_nt(
    const u16* __restrict__ A, const u16* __restrict__ B,
    const float* __restrict__ bias, void* __restrict__ C,
    int M, int N, int K)
{
  __shared__ u16 lsA[128 * 64];
  __shared__ u16 lsB[128 * 64];
  const int tid = threadIdx.x;
  const int wave = tid >> 6, lane = tid & 63;
  const int tm = blockIdx.y * 128, tn = blockIdx.x * 128;
  const int wr = wave >> 1, wc = wave & 1;
  const int lrow = lane >> 3, lcol = (lane & 7) * 8;
  const int il = lane & 15, g = lane >> 4;

  f32x4 acc[4][4] = {};

  for (int k0 = 0; k0 < K; k0 += 64) {
#pragma unroll
    for (int i = 0; i < 4; ++i) {
      int c = wave * 4 + i;
      const u16* ga = A + (size_t)(tm + c * 8 + lrow) * K + k0 + lcol;
      __builtin_amdgcn_global_load_lds((const __attribute__((address_space(1))) void*)ga,
                                       (__attribute__((address_space(3))) void*)&lsA[c * 512],
                                       16, 0, 0);
    }
#pragma unroll
    for (int i = 0; i < 4; ++i) {
      int c = wave * 4 + i;
      const u16* gb = B + (size_t)(tn + c * 8 + lrow) * K + k0 + lcol;
      __builtin_amdgcn_global_load_lds((const __attribute__((address_space(1))) void*)gb,
                                       (__attribute__((address_space(3))) void*)&lsB[c * 512],
                                       16, 0, 0);
    }
    __syncthreads();

#pragma unroll
    for (int kk = 0; kk < 2; ++kk) {
      s16x8 af[4], bfr[4];
#pragma unroll
      for (int i = 0; i < 4; ++i)
        af[i] = *(const s16x8*)&lsA[(wr * 64 + i * 16 + il) * 64 + kk * 32 + g * 8];
#pragma unroll
      for (int j = 0; j < 4; ++j)
        bfr[j] = *(const s16x8*)&lsB[(wc * 64 + j * 16 + il) * 64 + kk * 32 + g * 8];
#pragma unroll
      for (int i = 0; i < 4; ++i)
#pragma unroll
        for (int j = 0; j < 4; ++j)
          acc[i][j] = __builtin_amdgcn_mfma_f32_16x16x32_bf16(af[i], bfr[j], acc[i][j], 0, 0, 0);
    }
    __syncthreads();
  }

#pragma unroll
  for (int i = 0; i < 4; ++i) {
    const int row0 = tm + wr * 64 + i * 16 + g * 4;
#pragma unroll
    for (int j = 0; j < 4; ++j) {
      const int col = tn + wc * 64 + j * 16 + il;
      const float bb = bias[col];
#pragma unroll
      for (int r = 0; r < 4; ++r) {
        float v = acc[i][j][r] + bb;
        if (QKV_SCALE) { if (col < 768) v *= 0.125f; }
        if (STORE_BF16) ((u16*)C)[(size_t)(row0 + r) * N + col] = f2bf(v);
        else            ((float*)C)[(size_t)(row0 + r) * N + col] = v;
      }
    }
  }
}

// ---------------- V transpose: qkv V-block -> vT[b][h][e][k] ----------------
// 64x64 tiles through swizzled LDS; read+write phases both ~2-way conflict max.
__global__ __launch_bounds__(256) void transpose_v(const u16* __restrict__ qkv,
                                                   u16* __restrict__ vT) {
  __shared__ u16 T[64 * 64];
  const int kt = blockIdx.x, h = blockIdx.y, b = blockIdx.z;
  const int t = threadIdx.x;
  {
    const int k = t >> 2, c = (t & 3) * 16;
    const u16* src = qkv + (size_t)(b * 1024 + kt * 64 + k) * 2304 + 1536 + h * 64 + c;
    const int sw = ((k >> 3) & 7) << 4;  // swizzle on bits 4-6 of col byte, keyed by k>>3
#pragma unroll
    for (int s2 = 0; s2 < 2; ++s2) {
      s16x8 v = *(const s16x8*)(src + s2 * 8);
      *(s16x8*)((char*)T + k * 128 + (((c + s2 * 8) * 2) ^ sw)) = v;
    }
  }
  __syncthreads();
  const int w = t >> 6, l = t & 63;
  const int kj = (l & 7) * 8;
  const int sw = (l & 7) << 4;  // (kj+j)>>3 == l&7 for j<8
#pragma unroll
  for (int i = 0; i < 2; ++i) {
    const int e = w * 16 + i * 8 + (l >> 3);
    u16x8 o;
#pragma unroll
    for (int j = 0; j < 8; ++j)
      o[j] = *(const u16*)((const char*)T + (kj + j) * 128 + ((e * 2) ^ sw));
    *(u16x8*)(vT + ((size_t)(b * 12 + h) * 64 + e) * 1024 + kt * 64 + kj) = o;
  }
}

// ---------------- flash attention, swapped-operand structure ----------------
// grid 1536 (192 bh x 8 qblocks, XCD-co-located), block 256 = 4 waves.
// Each wave: 32 queries. KV tile 64. K and V^T staged linearly via
// global_load_lds with pre-swizzled source (XOR (row&7)<<4 on col byte);
// ds_read_b128 uses the same XOR -> conflict-free.
__global__ __launch_bounds__(256) void attn_fwd(const u16* __restrict__ qkv,
                                                const u16* __restrict__ vT,
                                                u16* __restrict__ concat)
{
  __shared__ u16 Kl[64 * 64];
  __shared__ u16 Vl[64 * 64];
  __shared__ u16 Pl[4][32 * 72];

  const int tid = threadIdx.x, wave = tid >> 6, lane = tid & 63;
  const int wg = blockIdx.x;
  const int bh = (wg & 7) | ((wg >> 6) << 3);   // same bh -> same (wg%8) -> same XCD
  const int qb = (wg >> 3) & 7;
  const int b = bh / 12, h = bh % 12;
  const int g = lane >> 4, il = lane & 15;
  const int qs0 = qb * 128 + wave * 32;

  const char* qkvB = (const char*)qkv;
  const size_t rowB = (size_t)b * 1024 * 4608;
  const char* vtB = (const char*)vT + (size_t)bh * 64 * 2048;

  // Q B-frags: lane holds Q[qs0 + q2*16 + il][kk*32 + g*8 + j] (scale folded upstream)
  s16x8 qf[2][2];
#pragma unroll
  for (int q2 = 0; q2 < 2; ++q2) {
    const char* qp = qkvB + rowB + (size_t)(qs0 + q2 * 16 + il) * 4608 + h * 128 + g * 16;
#pragma unroll
    for (int kk = 0; kk < 2; ++kk)
      qf[q2][kk] = *(const s16x8*)(qp + kk * 64);
  }

  float m_[2], l_[2];
  f32x4 accO[2][4] = {};
  m_[0] = m_[1] = -1e30f; l_[0] = l_[1] = 0.f;

  const int Lr = lane >> 3, Lc = lane & 7;
  const int colb = (Lc * 16) ^ ((Lr & 7) << 4);  // logical col byte for this lane's granule

  for (int kv0 = 0; kv0 < 1024; kv0 += 64) {
    // ---- stage K rows + V^T rows, linear LDS dest, swizzled global source ----
#pragma unroll
    for (int i = 0; i < 2; ++i) {
      const int row = wave * 16 + i * 8 + Lr;
      const char* ks = qkvB + rowB + (size_t)(kv0 + row) * 4608 + 1536 + h * 128 + colb;
      __builtin_amdgcn_global_load_lds((const __attribute__((address_space(1))) void*)ks,
          (__attribute__((address_space(3))) void*)(Kl + (wave * 16 + i * 8) * 64), 16, 0, 0);
      const char* vs = vtB + (size_t)row * 2048 + kv0 * 2 + colb;
      __builtin_amdgcn_global_load_lds((const __attribute__((address_space(1))) void*)vs,
          (__attribute__((address_space(3))) void*)(Vl + (wave * 16 + i * 8) * 64), 16, 0, 0);
    }
    __syncthreads();

    // ---- S^T = mfma(K, Q): lane holds S[k = kt*16 + g*4 + r][q = qs0 + q2*16 + il] ----
    f32x4 st[4][2] = {};
#pragma unroll
    for (int kt = 0; kt < 4; ++kt)
#pragma unroll
      for (int kk = 0; kk < 2; ++kk) {
        const int cb = (kk * 64 + g * 16) ^ ((il & 7) << 4);
        s16x8 kf = *(const s16x8*)((const char*)Kl + (kt * 16 + il) * 128 + cb);
        st[kt][0] = __builtin_amdgcn_mfma_f32_16x16x32_bf16(kf, qf[0][kk], st[kt][0], 0, 0, 0);
        st[kt][1] = __builtin_amdgcn_mfma_f32_16x16x32_bf16(kf, qf[1][kk], st[kt][1], 0, 0, 0);
      }

    // ---- online softmax: per-lane 16 scores of one query; 2 shfl per reduce ----
    float scq[2];
#pragma unroll
    for (int q2 = 0; q2 < 2; ++q2) {
      float c0 = fmaxf(fmaxf(st[0][q2][0], st[0][q2][1]), fmaxf(st[0][q2][2], st[0][q2][3]));
      float c1 = fmaxf(fmaxf(st[1][q2][0], st[1][q2][1]), fmaxf(st[1][q2][2], st[1][q2][3]));
      float c2 = fmaxf(fmaxf(st[2][q2][0], st[2][q2][1]), fmaxf(st[2][q2][2], st[2][q2][3]));
      float c3 = fmaxf(fmaxf(st[3][q2][0], st[3][q2][1]), fmaxf(st[3][q2][2], st[3][q2][3]));
      float cm = fmaxf(fmaxf(c0, c1), fmaxf(c2, c3));
      cm = fmaxf(cm, __shfl_xor(cm, 16));
      cm = fmaxf(cm, __shfl_xor(cm, 32));
      const float nm = fmaxf(m_[q2], cm);
      const float sc = exp2f((m_[q2] - nm) * LOG2E);
      m_[q2] = nm;
      float cs = 0.f;
#pragma unroll
      for (int kt = 0; kt < 4; ++kt) {
        u16x4 pk;
#pragma unroll
        for (int r = 0; r < 4; ++r) {
          const float pv = exp2f((st[kt][q2][r] - nm) * LOG2E);
          cs += pv;
          pk[r] = f2bf(pv);
        }
        // P[q][k]: row q2*16+il... no: row index is the QUERY this lane owns = il
        *(u16x4*)((char*)&Pl[wave][0] + (q2 * 16 + il) * 144 + (kt * 16 + g * 4) * 2) = pk;
      }
      cs += __shfl_xor(cs, 16);
      cs += __shfl_xor(cs, 32);
      l_[q2] = l_[q2] * sc + cs;
      scq[q2] = sc;
    }

    // ---- rescale accO (O rows are g*4+r; broadcast that query's scale) ----
#pragma unroll
    for (int q2 = 0; q2 < 2; ++q2)
#pragma unroll
      for (int r = 0; r < 4; ++r) {
        const float sb = __shfl(scq[q2], (g * 4 + r) | (lane & 48));
#pragma unroll
        for (int je = 0; je < 4; ++je) accO[q2][je][r] *= sb;
      }

    // ---- PV: O[q][e] += P * V ----
#pragma unroll
    for (int kk = 0; kk < 2; ++kk) {
      s16x8 pa[2];
#pragma unroll
      for (int q2 = 0; q2 < 2; ++q2)
        pa[q2] = *(const s16x8*)((char*)&Pl[wave][0] + (q2 * 16 + il) * 144 + kk * 64 + g * 16);
#pragma unroll
      for (int je = 0; je < 4; ++je) {
        const int cb = (kk * 64 + g * 16) ^ ((il & 7) << 4);
        s16x8 vf = *(const s16x8*)((const char*)Vl + (je * 16 + il) * 128 + cb);
        accO[0][je] = __builtin_amdgcn_mfma_f32_16x16x32_bf16(pa[0], vf, accO[0][je], 0, 0, 0);
        accO[1][je] = __builtin_amdgcn_mfma_f32_16x16x32_bf16(pa[1], vf, accO[1][je], 0, 0, 0);
      }
    }
    __syncthreads();
  }

  // ---- epilogue ----
#pragma unroll
  for (int q2 = 0; q2 < 2; ++q2) {
    const float linv = 1.f / l_[q2];
#pragma unroll
    for (int r = 0; r < 4; ++r) {
      const float lb = __shfl(linv, (g * 4 + r) | (lane & 48));
      const size_t orow = (size_t)b * 1024 + qs0 + q2 * 16 + g * 4 + r;
#pragma unroll
      for (int je = 0; je < 4; ++je)
        concat[orow * 768 + h * 64 + je * 16 + il] = f2bf(accO[q2][je][r] * lb);
    }
  }
}

// ---------------- launch ----------------
extern "C" void kernel_launch(void* const* d_in, const int* in_sizes, int n_in,
                              void* d_out, int out_size, void* d_ws, size_t ws_size,
                              hipStream_t stream) {
  const float* x  = (const float*)d_in[0];
  const float* Wq = (const float*)d_in[1];
  const float* bq = (const float*)d_in[2];
  const float* Wk = (const float*)d_in[3];
  const float* bk = (const float*)d_in[4];
  const float* Wv = (const float*)d_in[5];
  const float* bv = (const float*)d_in[6];
  const float* Wo = (const float*)d_in[7];
  const float* bo = (const float*)d_in[8];

  const size_t XN = (size_t)16384 * 768;
  const size_t WN = (size_t)768 * 768;

  u16* xb   = (u16*)d_ws;                  // [16384,768] bf16 (later aliased as concat)
  u16* wqkv = xb + XN;                     // [2304,768]
  u16* wo   = wqkv + 3 * WN;               // [768,768]
  float* bqkv = (float*)(wo + WN);         // [2304] fp32
  u16* qkv  = (u16*)(bqkv + 2304);         // [16384,2304]
  u16* vt   = qkv + (size_t)16384 * 2304;  // [192,64,1024] = vT[b][h][e][k]
  u16* cc   = xb;

  cvt_bf16<<<(int)(XN / 4 + 255) / 256, 256, 0, stream>>>(x, xb, (int)(XN / 4));
  cvt_bf16<<<(int)(WN / 4 + 255) / 256, 256, 0, stream>>>(Wq, wqkv, (int)(WN / 4));
  cvt_bf16<<<(int)(WN / 4 + 255) / 256, 256, 0, stream>>>(Wk, wqkv + WN, (int)(WN / 4));
  cvt_bf16<<<(int)(WN / 4 + 255) / 256, 256, 0, stream>>>(Wv, wqkv + 2 * WN, (int)(WN / 4));
  cvt_bf16<<<(int)(WN / 4 + 255) / 256, 256, 0, stream>>>(Wo, wo, (int)(WN / 4));
  hipMemcpyAsync(bqkv,        bq, 768 * sizeof(float), hipMemcpyDeviceToDevice, stream);
  hipMemcpyAsync(bqkv + 768,  bk, 768 * sizeof(float), hipMemcpyDeviceToDevice, stream);
  hipMemcpyAsync(bqkv + 1536, bv, 768 * sizeof(float), hipMemcpyDeviceToDevice, stream);

  gemm_nt<1, 1><<<dim3(2304 / 128, 16384 / 128), 256, 0, stream>>>(
      xb, wqkv, bqkv, qkv, 16384, 2304, 768);

  transpose_v<<<dim3(16, 12, 16), 256, 0, stream>>>(qkv, vt);

  attn_fwd<<<1536, 256, 0, stream>>>(qkv, vt, cc);

  gemm_nt<0, 0><<<dim3(768 / 128, 16384 / 128), 256, 0, stream>>>(
      cc, wo, bo, d_out, 16384, 768, 768);
}

// Round 3
// 256.629 us; speedup vs baseline: 1.5870x; 1.1636x over previous
//
#include <hip/hip_runtime.h>
#include <hip/hip_bf16.h>

typedef unsigned short u16;
typedef unsigned int u32;
typedef __attribute__((ext_vector_type(2))) unsigned int u32x2;
typedef __attribute__((ext_vector_type(4))) unsigned int u32x4;
typedef __attribute__((ext_vector_type(4))) float f32x4;
typedef __attribute__((ext_vector_type(16))) float f32x16;
typedef __attribute__((ext_vector_type(8))) short s16x8;
typedef __attribute__((ext_vector_type(4))) unsigned short u16x4;
typedef __attribute__((ext_vector_type(8))) unsigned short u16x8;

#define LOG2E 1.44269504088896f
// QKV GEMM folds 1/sqrt(64) * log2e into Q so attn scores are log2-domain
#define QSCALE 0.18033688011112042f

__device__ inline u16 f2bf(float f) {
  union { float f; unsigned u; } x; x.f = f;
  unsigned r = x.u + 0x7FFFu + ((x.u >> 16) & 1u);
  return (u16)(r >> 16);
}

__device__ inline u32 cvtpk(float lo, float hi) {
  u32 r;
  asm("v_cvt_pk_bf16_f32 %0, %1, %2" : "=v"(r) : "v"(lo), "v"(hi));
  return r;
}

// v_permlane32_swap_b32: lanes 32-63 of a exchange with lanes 0-31 of b
__device__ inline void pl32swap(u32& a, u32& b) {
  asm("v_permlane32_swap_b32 %0, %1" : "+v"(a), "+v"(b));
}

// ---------------- fp32 -> bf16 convert ----------------
__global__ void cvt_bf16(const float* __restrict__ src, u16* __restrict__ dst, int n4) {
  int i = blockIdx.x * blockDim.x + threadIdx.x;
  if (i < n4) {
    const float4 v = ((const float4*)src)[i];
    u16x4 o;
    o[0] = f2bf(v.x); o[1] = f2bf(v.y); o[2] = f2bf(v.z); o[3] = f2bf(v.w);
    ((u16x4*)dst)[i] = o;
  }
}

// ---------------- NT GEMM (verified rounds 1-2) ----------------
template<int STORE_BF16, int QKV_SCALE>
__global__ __launch_bounds__(256) void gemm_nt(
    const u16* __restrict__ A, const u16* __restrict__ B,
    const float* __restrict__ bias, void* __restrict__ C,
    int M, int N, int K)
{
  __shared__ u16 lsA[128 * 64];
  __shared__ u16 lsB[128 * 64];
  const int tid = threadIdx.x;
  const int wave = tid >> 6, lane = tid & 63;
  const int tm = blockIdx.y * 128, tn = blockIdx.x * 128;
  const int wr = wave >> 1, wc = wave & 1;
  const int lrow = lane >> 3, lcol = (lane & 7) * 8;
  const int il = lane & 15, g = lane >> 4;

  f32x4 acc[4][4] = {};

  for (int k0 = 0; k0 < K; k0 += 64) {
#pragma unroll
    for (int i = 0; i < 4; ++i) {
      int c = wave * 4 + i;
      const u16* ga = A + (size_t)(tm + c * 8 + lrow) * K + k0 + lcol;
      __builtin_amdgcn_global_load_lds((const __attribute__((address_space(1))) void*)ga,
                                       (__attribute__((address_space(3))) void*)&lsA[c * 512],
                                       16, 0, 0);
    }
#pragma unroll
    for (int i = 0; i < 4; ++i) {
      int c = wave * 4 + i;
      const u16* gb = B + (size_t)(tn + c * 8 + lrow) * K + k0 + lcol;
      __builtin_amdgcn_global_load_lds((const __attribute__((address_space(1))) void*)gb,
                                       (__attribute__((address_space(3))) void*)&lsB[c * 512],
                                       16, 0, 0);
    }
    __syncthreads();

#pragma unroll
    for (int kk = 0; kk < 2; ++kk) {
      s16x8 af[4], bfr[4];
#pragma unroll
      for (int i = 0; i < 4; ++i)
        af[i] = *(const s16x8*)&lsA[(wr * 64 + i * 16 + il) * 64 + kk * 32 + g * 8];
#pragma unroll
      for (int j = 0; j < 4; ++j)
        bfr[j] = *(const s16x8*)&lsB[(wc * 64 + j * 16 + il) * 64 + kk * 32 + g * 8];
#pragma unroll
      for (int i = 0; i < 4; ++i)
#pragma unroll
        for (int j = 0; j < 4; ++j)
          acc[i][j] = __builtin_amdgcn_mfma_f32_16x16x32_bf16(af[i], bfr[j], acc[i][j], 0, 0, 0);
    }
    __syncthreads();
  }

#pragma unroll
  for (int i = 0; i < 4; ++i) {
    const int row0 = tm + wr * 64 + i * 16 + g * 4;
#pragma unroll
    for (int j = 0; j < 4; ++j) {
      const int col = tn + wc * 64 + j * 16 + il;
      const float bb = bias[col];
#pragma unroll
      for (int r = 0; r < 4; ++r) {
        float v = acc[i][j][r] + bb;
        if (QKV_SCALE) { if (col < 768) v *= QSCALE; }
        if (STORE_BF16) ((u16*)C)[(size_t)(row0 + r) * N + col] = f2bf(v);
        else            ((float*)C)[(size_t)(row0 + r) * N + col] = v;
      }
    }
  }
}

// ---------------- V transpose: qkv V-block -> vT[b][h][e][k] (verified r2) ----------------
__global__ __launch_bounds__(256) void transpose_v(const u16* __restrict__ qkv,
                                                   u16* __restrict__ vT) {
  __shared__ u16 T[64 * 64];
  const int kt = blockIdx.x, h = blockIdx.y, b = blockIdx.z;
  const int t = threadIdx.x;
  {
    const int k = t >> 2, c = (t & 3) * 16;
    const u16* src = qkv + (size_t)(b * 1024 + kt * 64 + k) * 2304 + 1536 + h * 64 + c;
    const int sw = ((k >> 3) & 7) << 4;
#pragma unroll
    for (int s2 = 0; s2 < 2; ++s2) {
      s16x8 v = *(const s16x8*)(src + s2 * 8);
      *(s16x8*)((char*)T + k * 128 + (((c + s2 * 8) * 2) ^ sw)) = v;
    }
  }
  __syncthreads();
  const int w = t >> 6, l = t & 63;
  const int kj = (l & 7) * 8;
  const int sw = (l & 7) << 4;
#pragma unroll
  for (int i = 0; i < 2; ++i) {
    const int e = w * 16 + i * 8 + (l >> 3);
    u16x8 o;
#pragma unroll
    for (int j = 0; j < 8; ++j)
      o[j] = *(const u16*)((const char*)T + (kj + j) * 128 + ((e * 2) ^ sw));
    *(u16x8*)(vT + ((size_t)(b * 12 + h) * 64 + e) * 1024 + kt * 64 + kj) = o;
  }
}

// ---------------- flash attention: 32x32 MFMA, fully in-register softmax ----------------
// grid 1536 (192 bh x 8 qblocks, XCD-co-located), 4 waves x 32 queries.
// S^T = mfma32(K, Q)  -> lane owns query q=lane&31 (cols of S^T)
// O^T = mfma32(V^T, P^T) -> lane owns query q (cols of O^T); rescale/div lane-uniform.
// P: C-layout -> B-frag via cvt_pk + permlane32_swap (no LDS).
__global__ __launch_bounds__(256) void attn_fwd(const u16* __restrict__ qkv,
                                                const u16* __restrict__ vT,
                                                u16* __restrict__ concat)
{
  __shared__ u16 Kl[64 * 64];
  __shared__ u16 Vl[64 * 64];

  const int tid = threadIdx.x, wave = tid >> 6, lane = tid & 63;
  const int wg = blockIdx.x;
  const int bh = (wg & 7) | ((wg >> 6) << 3);
  const int qb = (wg >> 3) & 7;
  const int b = bh / 12, h = bh % 12;
  const int q = lane & 31, hi = lane >> 5;
  const int qs0 = qb * 128 + wave * 32;

  const char* qkvB = (const char*)qkv;
  const size_t rowB = (size_t)b * 1024 * 4608;
  const char* vtB = (const char*)vT + (size_t)bh * 64 * 2048;

  // Q B-frags: qf[s][j] = Q[qs0+q][s*16 + hi*8 + j]  (0.125*log2e pre-folded)
  s16x8 qf[4];
  {
    const char* qp = qkvB + rowB + (size_t)(qs0 + q) * 4608 + h * 128 + hi * 16;
#pragma unroll
    for (int s = 0; s < 4; ++s) qf[s] = *(const s16x8*)(qp + s * 32);
  }

  float m_ = -3.0e38f, l_ = 0.f;
  f32x16 accO[2] = {};

  const int Lr = lane >> 3, Lc = lane & 7;
  const int colb = (Lc * 16) ^ ((Lr & 7) << 4);  // pre-swizzled source col
  const int swk = (q & 7) << 4;                  // read-side swizzle key

  for (int kv0 = 0; kv0 < 1024; kv0 += 64) {
    // ---- stage K rows + V^T rows (linear LDS dest, swizzled global source) ----
#pragma unroll
    for (int i = 0; i < 2; ++i) {
      const int row = wave * 16 + i * 8 + Lr;
      const char* ks = qkvB + rowB + (size_t)(kv0 + row) * 4608 + 1536 + h * 128 + colb;
      __builtin_amdgcn_global_load_lds((const __attribute__((address_space(1))) void*)ks,
          (__attribute__((address_space(3))) void*)(Kl + (wave * 16 + i * 8) * 64), 16, 0, 0);
      const char* vs = vtB + (size_t)row * 2048 + kv0 * 2 + colb;
      __builtin_amdgcn_global_load_lds((const __attribute__((address_space(1))) void*)vs,
          (__attribute__((address_space(3))) void*)(Vl + (wave * 16 + i * 8) * 64), 16, 0, 0);
    }
    __syncthreads();

    // ---- S^T[64k][32q]: lane holds k=(kb*32)+(r&3)+8*(r>>2)+4*hi, col q ----
    f32x16 st[2] = {};
    __builtin_amdgcn_s_setprio(1);
#pragma unroll
    for (int s = 0; s < 4; ++s) {
      const int cb = (s * 32 + hi * 16) ^ swk;
      s16x8 k0 = *(const s16x8*)((const char*)Kl + q * 128 + cb);
      s16x8 k1 = *(const s16x8*)((const char*)Kl + (32 + q) * 128 + cb);
      st[0] = __builtin_amdgcn_mfma_f32_32x32x16_bf16(k0, qf[s], st[0], 0, 0, 0);
      st[1] = __builtin_amdgcn_mfma_f32_32x32x16_bf16(k1, qf[s], st[1], 0, 0, 0);
    }
    __builtin_amdgcn_s_setprio(0);

    // ---- online softmax, log2 domain, per-lane single query ----
    float pmax = st[0][0];
#pragma unroll
    for (int r = 1; r < 16; ++r) pmax = fmaxf(pmax, st[0][r]);
#pragma unroll
    for (int r = 0; r < 16; ++r) pmax = fmaxf(pmax, st[1][r]);
    pmax = fmaxf(pmax, __shfl_xor(pmax, 32));

    const bool need = __any(pmax > m_ + 8.f);  // defer-max (T13)
    float sc = 1.f;
    if (need) {
      const float nm = fmaxf(m_, pmax);
      sc = __builtin_amdgcn_exp2f(m_ - nm);
      m_ = nm;
    }
    float cs = 0.f;
#pragma unroll
    for (int kb = 0; kb < 2; ++kb)
#pragma unroll
      for (int r = 0; r < 16; ++r) {
        const float pv = __builtin_amdgcn_exp2f(st[kb][r] - m_);
        st[kb][r] = pv;
        cs += pv;
      }
    cs += __shfl_xor(cs, 32);
    if (need) {
      l_ = l_ * sc + cs;
#pragma unroll
      for (int eb = 0; eb < 2; ++eb)
#pragma unroll
        for (int r = 0; r < 16; ++r) accO[eb][r] *= sc;
    } else {
      l_ += cs;
    }

    // ---- P C-layout -> B-frags: cvt_pk pairs + permlane32_swap (T12) ----
    s16x8 pa[4];
#pragma unroll
    for (int kb = 0; kb < 2; ++kb)
#pragma unroll
      for (int ks = 0; ks < 2; ++ks) {
        u32 A0 = cvtpk(st[kb][ks * 8 + 0], st[kb][ks * 8 + 1]);
        u32 A1 = cvtpk(st[kb][ks * 8 + 2], st[kb][ks * 8 + 3]);
        u32 B0 = cvtpk(st[kb][ks * 8 + 4], st[kb][ks * 8 + 5]);
        u32 B1 = cvtpk(st[kb][ks * 8 + 6], st[kb][ks * 8 + 7]);
        pl32swap(A0, B0);
        pl32swap(A1, B1);
        u32x4 w = {A0, A1, B0, B1};
        pa[kb * 2 + ks] = __builtin_bit_cast(s16x8, w);
      }

    // ---- O^T[64e][32q] += V^T · P^T ----
    __builtin_amdgcn_s_setprio(1);
#pragma unroll
    for (int ksub = 0; ksub < 4; ++ksub) {
      const int cb = (ksub * 32 + hi * 16) ^ swk;
      s16x8 v0 = *(const s16x8*)((const char*)Vl + q * 128 + cb);
      s16x8 v1 = *(const s16x8*)((const char*)Vl + (32 + q) * 128 + cb);
      accO[0] = __builtin_amdgcn_mfma_f32_32x32x16_bf16(v0, pa[ksub], accO[0], 0, 0, 0);
      accO[1] = __builtin_amdgcn_mfma_f32_32x32x16_bf16(v1, pa[ksub], accO[1], 0, 0, 0);
    }
    __builtin_amdgcn_s_setprio(0);
    __syncthreads();
  }

  // ---- epilogue: lane-uniform 1/l, direct global u16x4 stores ----
  const float linv = __builtin_amdgcn_rcpf(l_);
  u16* crow = concat + ((size_t)b * 1024 + qs0 + q) * 768 + h * 64;
#pragma unroll
  for (int eb = 0; eb < 2; ++eb)
#pragma unroll
    for (int rq = 0; rq < 4; ++rq) {
      // regs 4rq..4rq+3 -> e = eb*32 + 8*rq + 4*hi + {0..3}
      u32 w0 = cvtpk(accO[eb][rq * 4 + 0] * linv, accO[eb][rq * 4 + 1] * linv);
      u32 w1 = cvtpk(accO[eb][rq * 4 + 2] * linv, accO[eb][rq * 4 + 3] * linv);
      u32x2 w = {w0, w1};
      *(u16x4*)(crow + eb * 32 + rq * 8 + hi * 4) = __builtin_bit_cast(u16x4, w);
    }
}

// ---------------- launch ----------------
extern "C" void kernel_launch(void* const* d_in, const int* in_sizes, int n_in,
                              void* d_out, int out_size, void* d_ws, size_t ws_size,
                              hipStream_t stream) {
  const float* x  = (const float*)d_in[0];
  const float* Wq = (const float*)d_in[1];
  const float* bq = (const float*)d_in[2];
  const float* Wk = (const float*)d_in[3];
  const float* bk = (const float*)d_in[4];
  const float* Wv = (const float*)d_in[5];
  const float* bv = (const float*)d_in[6];
  const float* Wo = (const float*)d_in[7];
  const float* bo = (const float*)d_in[8];

  const size_t XN = (size_t)16384 * 768;
  const size_t WN = (size_t)768 * 768;

  u16* xb   = (u16*)d_ws;                  // [16384,768] bf16 (later aliased as concat)
  u16* wqkv = xb + XN;                     // [2304,768]
  u16* wo   = wqkv + 3 * WN;               // [768,768]
  float* bqkv = (float*)(wo + WN);         // [2304] fp32
  u16* qkv  = (u16*)(bqkv + 2304);         // [16384,2304]
  u16* vt   = qkv + (size_t)16384 * 2304;  // [192,64,1024] = vT[b][h][e][k]
  u16* cc   = xb;

  cvt_bf16<<<(int)(XN / 4 + 255) / 256, 256, 0, stream>>>(x, xb, (int)(XN / 4));
  cvt_bf16<<<(int)(WN / 4 + 255) / 256, 256, 0, stream>>>(Wq, wqkv, (int)(WN / 4));
  cvt_bf16<<<(int)(WN / 4 + 255) / 256, 256, 0, stream>>>(Wk, wqkv + WN, (int)(WN / 4));
  cvt_bf16<<<(int)(WN / 4 + 255) / 256, 256, 0, stream>>>(Wv, wqkv + 2 * WN, (int)(WN / 4));
  cvt_bf16<<<(int)(WN / 4 + 255) / 256, 256, 0, stream>>>(Wo, wo, (int)(WN / 4));
  hipMemcpyAsync(bqkv,        bq, 768 * sizeof(float), hipMemcpyDeviceToDevice, stream);
  hipMemcpyAsync(bqkv + 768,  bk, 768 * sizeof(float), hipMemcpyDeviceToDevice, stream);
  hipMemcpyAsync(bqkv + 1536, bv, 768 * sizeof(float), hipMemcpyDeviceToDevice, stream);

  gemm_nt<1, 1><<<dim3(2304 / 128, 16384 / 128), 256, 0, stream>>>(
      xb, wqkv, bqkv, qkv, 16384, 2304, 768);

  transpose_v<<<dim3(16, 12, 16), 256, 0, stream>>>(qkv, vt);

  attn_fwd<<<1536, 256, 0, stream>>>(qkv, vt, cc);

  gemm_nt<0, 0><<<dim3(768 / 128, 16384 / 128), 256, 0, stream>>>(
      cc, wo, bo, d_out, 16384, 768, 768);
}

// Round 4
// 221.156 us; speedup vs baseline: 1.8415x; 1.1604x over previous
//
#include <hip/hip_runtime.h>
#include <hip/hip_bf16.h>

typedef unsigned short u16;
typedef unsigned int u32;
typedef __attribute__((ext_vector_type(2))) unsigned int u32x2;
typedef __attribute__((ext_vector_type(4))) unsigned int u32x4;
typedef __attribute__((ext_vector_type(4))) float f32x4;
typedef __attribute__((ext_vector_type(16))) float f32x16;
typedef __attribute__((ext_vector_type(8))) short s16x8;
typedef __attribute__((ext_vector_type(4))) unsigned short u16x4;
typedef __attribute__((ext_vector_type(8))) unsigned short u16x8;

#define LOG2E 1.44269504088896f
// QKV GEMM folds 1/sqrt(64) * log2e into Q so attn scores are log2-domain
#define QSCALE 0.18033688011112042f

#define BARRIER() do { __builtin_amdgcn_s_barrier(); __builtin_amdgcn_sched_barrier(0); } while (0)
#define WAIT_VM0() do { asm volatile("s_waitcnt vmcnt(0)" ::: "memory"); __builtin_amdgcn_sched_barrier(0); } while (0)

__device__ inline u16 f2bf(float f) {
  union { float f; unsigned u; } x; x.f = f;
  unsigned r = x.u + 0x7FFFu + ((x.u >> 16) & 1u);
  return (u16)(r >> 16);
}

__device__ inline u32 cvtpk(float lo, float hi) {
  u32 r;
  asm("v_cvt_pk_bf16_f32 %0, %1, %2" : "=v"(r) : "v"(lo), "v"(hi));
  return r;
}

__device__ inline void pl32swap(u32& a, u32& b) {
  asm("v_permlane32_swap_b32 %0, %1" : "+v"(a), "+v"(b));
}

// ---------------- fp32 -> bf16 convert ----------------
__global__ void cvt_bf16(const float* __restrict__ src, u16* __restrict__ dst, int n4) {
  int i = blockIdx.x * blockDim.x + threadIdx.x;
  if (i < n4) {
    const float4 v = ((const float4*)src)[i];
    u16x4 o;
    o[0] = f2bf(v.x); o[1] = f2bf(v.y); o[2] = f2bf(v.z); o[3] = f2bf(v.w);
    ((u16x4*)dst)[i] = o;
  }
}

// ---------------- 256x256 8-wave pipelined NT GEMM ----------------
// BK=64, 4 phases/K-tile, LDS double-buffered + XOR-swizzled (T2),
// prefetch-1 with counted overlap, raw barriers (no vmcnt drain per phase),
// setprio around MFMA clusters (T5), XCD-chunked grid (T1).
// C[m,n] = sum_k A[m,k] * B[n,k] + bias[n].
template<int STORE_BF16, int QKV_SCALE>
__global__ __launch_bounds__(512, 2) void gemm8(
    const u16* __restrict__ A, const u16* __restrict__ Bm,
    const float* __restrict__ bias, void* __restrict__ C,
    int N, int K, int ntiles)
{
  __shared__ char lds[131072];  // [buf][A 32K | B 32K]

  const int tid = threadIdx.x, wave = tid >> 6, lane = tid & 63;
  const int il = lane & 15, g = lane >> 4;
  const int Lr = lane >> 3, Lc = lane & 7;
  const int wm = wave >> 2, wn = wave & 3;

  // XCD swizzle (nwg % 8 == 0): XCD x owns contiguous orig range
  const int cpx = (int)gridDim.x >> 3;
  const int orig = (blockIdx.x & 7) * cpx + (blockIdx.x >> 3);
  const int tm = (orig / ntiles) * 256, tn = (orig % ntiles) * 256;

  const size_t Kb = (size_t)K * 2;
  const int colb = (Lc * 16) ^ (Lr << 4);  // inverse-swizzled source col (involution)

  auto stageA = [&](int buf, int half, int k0) {
    char* db = &lds[buf * 65536 + half * 16384 + wave * 1024];
#pragma unroll
    for (int q = 0; q < 2; ++q) {
      const int row = tm + half * 128 + q * 64 + wave * 8 + Lr;
      const char* src = (const char*)A + (size_t)row * Kb + k0 * 2 + colb;
      __builtin_amdgcn_global_load_lds((const __attribute__((address_space(1))) void*)src,
          (__attribute__((address_space(3))) void*)(db + q * 8192), 16, 0, 0);
    }
  };
  auto stageB = [&](int buf, int half, int k0) {
    char* db = &lds[buf * 65536 + 32768 + half * 16384 + wave * 1024];
#pragma unroll
    for (int q = 0; q < 2; ++q) {
      const int row = tn + half * 128 + q * 64 + wave * 8 + Lr;
      const char* src = (const char*)Bm + (size_t)row * Kb + k0 * 2 + colb;
      __builtin_amdgcn_global_load_lds((const __attribute__((address_space(1))) void*)src,
          (__attribute__((address_space(3))) void*)(db + q * 8192), 16, 0, 0);
    }
  };
  auto ldA = [&](int buf, int fr, int kk) -> s16x8 {
    const int row = wm * 128 + fr * 16 + il;
    const int cb = (kk * 64 + g * 16) ^ ((il & 7) << 4);
    return *(const s16x8*)&lds[buf * 65536 + row * 128 + cb];
  };
  auto ldB = [&](int buf, int fc, int kk) -> s16x8 {
    const int row = wn * 64 + fc * 16 + il;
    const int cb = (kk * 64 + g * 16) ^ ((il & 7) << 4);
    return *(const s16x8*)&lds[buf * 65536 + 32768 + row * 128 + cb];
  };

  f32x4 acc[8][4] = {};
  const int nK = K >> 6;

  // prologue: full tile 0
  stageA(0, 0, 0); stageA(0, 1, 0); stageB(0, 0, 0); stageB(0, 1, 0);
  WAIT_VM0();
  BARRIER();

  for (int t = 0; t < nK; ++t) {
    const int cur = t & 1, nxt = cur ^ 1;
    const int k1 = (t + 1) << 6;
    const bool pf = (t + 1 < nK);

    s16x8 bf[4][2];

    // ---- phase 1: read all B-frags + A fr0-1 (12 b128); issue A prefetch ----
#pragma unroll
    for (int fc = 0; fc < 4; ++fc) { bf[fc][0] = ldB(cur, fc, 0); bf[fc][1] = ldB(cur, fc, 1); }
    {
      s16x8 a00 = ldA(cur, 0, 0), a01 = ldA(cur, 0, 1);
      s16x8 a10 = ldA(cur, 1, 0), a11 = ldA(cur, 1, 1);
      if (pf) { stageA(nxt, 0, k1); stageA(nxt, 1, k1); }
      BARRIER();
      __builtin_amdgcn_s_setprio(1);
#pragma unroll
      for (int fc = 0; fc < 4; ++fc) {
        acc[0][fc] = __builtin_amdgcn_mfma_f32_16x16x32_bf16(a00, bf[fc][0], acc[0][fc], 0, 0, 0);
        acc[0][fc] = __builtin_amdgcn_mfma_f32_16x16x32_bf16(a01, bf[fc][1], acc[0][fc], 0, 0, 0);
        acc[1][fc] = __builtin_amdgcn_mfma_f32_16x16x32_bf16(a10, bf[fc][0], acc[1][fc], 0, 0, 0);
        acc[1][fc] = __builtin_amdgcn_mfma_f32_16x16x32_bf16(a11, bf[fc][1], acc[1][fc], 0, 0, 0);
      }
      __builtin_amdgcn_s_setprio(0);
      BARRIER();
    }
    // ---- phase 2: A fr2-3; issue B prefetch ----
    {
      s16x8 a00 = ldA(cur, 2, 0), a01 = ldA(cur, 2, 1);
      s16x8 a10 = ldA(cur, 3, 0), a11 = ldA(cur, 3, 1);
      if (pf) { stageB(nxt, 0, k1); stageB(nxt, 1, k1); }
      BARRIER();
      __builtin_amdgcn_s_setprio(1);
#pragma unroll
      for (int fc = 0; fc < 4; ++fc) {
        acc[2][fc] = __builtin_amdgcn_mfma_f32_16x16x32_bf16(a00, bf[fc][0], acc[2][fc], 0, 0, 0);
        acc[2][fc] = __builtin_amdgcn_mfma_f32_16x16x32_bf16(a01, bf[fc][1], acc[2][fc], 0, 0, 0);
        acc[3][fc] = __builtin_amdgcn_mfma_f32_16x16x32_bf16(a10, bf[fc][0], acc[3][fc], 0, 0, 0);
        acc[3][fc] = __builtin_amdgcn_mfma_f32_16x16x32_bf16(a11, bf[fc][1], acc[3][fc], 0, 0, 0);
      }
      __builtin_amdgcn_s_setprio(0);
      BARRIER();
    }
    // ---- phase 3: A fr4-5 ----
    {
      s16x8 a00 = ldA(cur, 4, 0), a01 = ldA(cur, 4, 1);
      s16x8 a10 = ldA(cur, 5, 0), a11 = ldA(cur, 5, 1);
      BARRIER();
      __builtin_amdgcn_s_setprio(1);
#pragma unroll
      for (int fc = 0; fc < 4; ++fc) {
        acc[4][fc] = __builtin_amdgcn_mfma_f32_16x16x32_bf16(a00, bf[fc][0], acc[4][fc], 0, 0, 0);
        acc[4][fc] = __builtin_amdgcn_mfma_f32_16x16x32_bf16(a01, bf[fc][1], acc[4][fc], 0, 0, 0);
        acc[5][fc] = __builtin_amdgcn_mfma_f32_16x16x32_bf16(a10, bf[fc][0], acc[5][fc], 0, 0, 0);
        acc[5][fc] = __builtin_amdgcn_mfma_f32_16x16x32_bf16(a11, bf[fc][1], acc[5][fc], 0, 0, 0);
      }
      __builtin_amdgcn_s_setprio(0);
      BARRIER();
    }
    // ---- phase 4: A fr6-7; boundary wait ----
    {
      s16x8 a00 = ldA(cur, 6, 0), a01 = ldA(cur, 6, 1);
      s16x8 a10 = ldA(cur, 7, 0), a11 = ldA(cur, 7, 1);
      BARRIER();
      __builtin_amdgcn_s_setprio(1);
#pragma unroll
      for (int fc = 0; fc < 4; ++fc) {
        acc[6][fc] = __builtin_amdgcn_mfma_f32_16x16x32_bf16(a00, bf[fc][0], acc[6][fc], 0, 0, 0);
        acc[6][fc] = __builtin_amdgcn_mfma_f32_16x16x32_bf16(a01, bf[fc][1], acc[6][fc], 0, 0, 0);
        acc[7][fc] = __builtin_amdgcn_mfma_f32_16x16x32_bf16(a10, bf[fc][0], acc[7][fc], 0, 0, 0);
        acc[7][fc] = __builtin_amdgcn_mfma_f32_16x16x32_bf16(a11, bf[fc][1], acc[7][fc], 0, 0, 0);
      }
      __builtin_amdgcn_s_setprio(0);
      if (pf) WAIT_VM0();   // t+1's halves all in LDS after next barrier
      BARRIER();
    }
  }

  // ---- epilogue ----
#pragma unroll
  for (int fr = 0; fr < 8; ++fr) {
    const int row0 = tm + wm * 128 + fr * 16 + g * 4;
#pragma unroll
    for (int fc = 0; fc < 4; ++fc) {
      const int col = tn + wn * 64 + fc * 16 + il;
      const float bb = bias[col];
#pragma unroll
      for (int r = 0; r < 4; ++r) {
        float v = acc[fr][fc][r] + bb;
        if (QKV_SCALE) { if (col < 768) v *= QSCALE; }
        if (STORE_BF16) ((u16*)C)[(size_t)(row0 + r) * N + col] = f2bf(v);
        else            ((float*)C)[(size_t)(row0 + r) * N + col] = v;
      }
    }
  }
}

// ---------------- V transpose: qkv V-block -> vT[b][h][e][k] (verified r2) ----------------
__global__ __launch_bounds__(256) void transpose_v(const u16* __restrict__ qkv,
                                                   u16* __restrict__ vT) {
  __shared__ u16 T[64 * 64];
  const int kt = blockIdx.x, h = blockIdx.y, b = blockIdx.z;
  const int t = threadIdx.x;
  {
    const int k = t >> 2, c = (t & 3) * 16;
    const u16* src = qkv + (size_t)(b * 1024 + kt * 64 + k) * 2304 + 1536 + h * 64 + c;
    const int sw = ((k >> 3) & 7) << 4;
#pragma unroll
    for (int s2 = 0; s2 < 2; ++s2) {
      s16x8 v = *(const s16x8*)(src + s2 * 8);
      *(s16x8*)((char*)T + k * 128 + (((c + s2 * 8) * 2) ^ sw)) = v;
    }
  }
  __syncthreads();
  const int w = t >> 6, l = t & 63;
  const int kj = (l & 7) * 8;
  const int sw = (l & 7) << 4;
#pragma unroll
  for (int i = 0; i < 2; ++i) {
    const int e = w * 16 + i * 8 + (l >> 3);
    u16x8 o;
#pragma unroll
    for (int j = 0; j < 8; ++j)
      o[j] = *(const u16*)((const char*)T + (kj + j) * 128 + ((e * 2) ^ sw));
    *(u16x8*)(vT + ((size_t)(b * 12 + h) * 64 + e) * 1024 + kt * 64 + kj) = o;
  }
}

// ---------------- flash attention (verified r3): 32x32 MFMA, in-register softmax ----------------
__global__ __launch_bounds__(256) void attn_fwd(const u16* __restrict__ qkv,
                                                const u16* __restrict__ vT,
                                                u16* __restrict__ concat)
{
  __shared__ u16 Kl[64 * 64];
  __shared__ u16 Vl[64 * 64];

  const int tid = threadIdx.x, wave = tid >> 6, lane = tid & 63;
  const int wg = blockIdx.x;
  const int bh = (wg & 7) | ((wg >> 6) << 3);
  const int qb = (wg >> 3) & 7;
  const int b = bh / 12, h = bh % 12;
  const int q = lane & 31, hi = lane >> 5;
  const int qs0 = qb * 128 + wave * 32;

  const char* qkvB = (const char*)qkv;
  const size_t rowB = (size_t)b * 1024 * 4608;
  const char* vtB = (const char*)vT + (size_t)bh * 64 * 2048;

  s16x8 qf[4];
  {
    const char* qp = qkvB + rowB + (size_t)(qs0 + q) * 4608 + h * 128 + hi * 16;
#pragma unroll
    for (int s = 0; s < 4; ++s) qf[s] = *(const s16x8*)(qp + s * 32);
  }

  float m_ = -3.0e38f, l_ = 0.f;
  f32x16 accO[2] = {};

  const int Lr = lane >> 3, Lc = lane & 7;
  const int colb = (Lc * 16) ^ ((Lr & 7) << 4);
  const int swk = (q & 7) << 4;

  for (int kv0 = 0; kv0 < 1024; kv0 += 64) {
#pragma unroll
    for (int i = 0; i < 2; ++i) {
      const int row = wave * 16 + i * 8 + Lr;
      const char* ks = qkvB + rowB + (size_t)(kv0 + row) * 4608 + 1536 + h * 128 + colb;
      __builtin_amdgcn_global_load_lds((const __attribute__((address_space(1))) void*)ks,
          (__attribute__((address_space(3))) void*)(Kl + (wave * 16 + i * 8) * 64), 16, 0, 0);
      const char* vs = vtB + (size_t)row * 2048 + kv0 * 2 + colb;
      __builtin_amdgcn_global_load_lds((const __attribute__((address_space(1))) void*)vs,
          (__attribute__((address_space(3))) void*)(Vl + (wave * 16 + i * 8) * 64), 16, 0, 0);
    }
    __syncthreads();

    f32x16 st[2] = {};
    __builtin_amdgcn_s_setprio(1);
#pragma unroll
    for (int s = 0; s < 4; ++s) {
      const int cb = (s * 32 + hi * 16) ^ swk;
      s16x8 k0 = *(const s16x8*)((const char*)Kl + q * 128 + cb);
      s16x8 k1 = *(const s16x8*)((const char*)Kl + (32 + q) * 128 + cb);
      st[0] = __builtin_amdgcn_mfma_f32_32x32x16_bf16(k0, qf[s], st[0], 0, 0, 0);
      st[1] = __builtin_amdgcn_mfma_f32_32x32x16_bf16(k1, qf[s], st[1], 0, 0, 0);
    }
    __builtin_amdgcn_s_setprio(0);

    float pmax = st[0][0];
#pragma unroll
    for (int r = 1; r < 16; ++r) pmax = fmaxf(pmax, st[0][r]);
#pragma unroll
    for (int r = 0; r < 16; ++r) pmax = fmaxf(pmax, st[1][r]);
    pmax = fmaxf(pmax, __shfl_xor(pmax, 32));

    const bool need = __any(pmax > m_ + 8.f);
    float sc = 1.f;
    if (need) {
      const float nm = fmaxf(m_, pmax);
      sc = __builtin_amdgcn_exp2f(m_ - nm);
      m_ = nm;
    }
    float cs = 0.f;
#pragma unroll
    for (int kb = 0; kb < 2; ++kb)
#pragma unroll
      for (int r = 0; r < 16; ++r) {
        const float pv = __builtin_amdgcn_exp2f(st[kb][r] - m_);
        st[kb][r] = pv;
        cs += pv;
      }
    cs += __shfl_xor(cs, 32);
    if (need) {
      l_ = l_ * sc + cs;
#pragma unroll
      for (int eb = 0; eb < 2; ++eb)
#pragma unroll
        for (int r = 0; r < 16; ++r) accO[eb][r] *= sc;
    } else {
      l_ += cs;
    }

    s16x8 pa[4];
#pragma unroll
    for (int kb = 0; kb < 2; ++kb)
#pragma unroll
      for (int ks = 0; ks < 2; ++ks) {
        u32 A0 = cvtpk(st[kb][ks * 8 + 0], st[kb][ks * 8 + 1]);
        u32 A1 = cvtpk(st[kb][ks * 8 + 2], st[kb][ks * 8 + 3]);
        u32 B0 = cvtpk(st[kb][ks * 8 + 4], st[kb][ks * 8 + 5]);
        u32 B1 = cvtpk(st[kb][ks * 8 + 6], st[kb][ks * 8 + 7]);
        pl32swap(A0, B0);
        pl32swap(A1, B1);
        u32x4 w = {A0, A1, B0, B1};
        pa[kb * 2 + ks] = __builtin_bit_cast(s16x8, w);
      }

    __builtin_amdgcn_s_setprio(1);
#pragma unroll
    for (int ksub = 0; ksub < 4; ++ksub) {
      const int cb = (ksub * 32 + hi * 16) ^ swk;
      s16x8 v0 = *(const s16x8*)((const char*)Vl + q * 128 + cb);
      s16x8 v1 = *(const s16x8*)((const char*)Vl + (32 + q) * 128 + cb);
      accO[0] = __builtin_amdgcn_mfma_f32_32x32x16_bf16(v0, pa[ksub], accO[0], 0, 0, 0);
      accO[1] = __builtin_amdgcn_mfma_f32_32x32x16_bf16(v1, pa[ksub], accO[1], 0, 0, 0);
    }
    __builtin_amdgcn_s_setprio(0);
    __syncthreads();
  }

  const float linv = __builtin_amdgcn_rcpf(l_);
  u16* crow = concat + ((size_t)b * 1024 + qs0 + q) * 768 + h * 64;
#pragma unroll
  for (int eb = 0; eb < 2; ++eb)
#pragma unroll
    for (int rq = 0; rq < 4; ++rq) {
      u32 w0 = cvtpk(accO[eb][rq * 4 + 0] * linv, accO[eb][rq * 4 + 1] * linv);
      u32 w1 = cvtpk(accO[eb][rq * 4 + 2] * linv, accO[eb][rq * 4 + 3] * linv);
      u32x2 w = {w0, w1};
      *(u16x4*)(crow + eb * 32 + rq * 8 + hi * 4) = __builtin_bit_cast(u16x4, w);
    }
}

// ---------------- launch ----------------
extern "C" void kernel_launch(void* const* d_in, const int* in_sizes, int n_in,
                              void* d_out, int out_size, void* d_ws, size_t ws_size,
                              hipStream_t stream) {
  const float* x  = (const float*)d_in[0];
  const float* Wq = (const float*)d_in[1];
  const float* bq = (const float*)d_in[2];
  const float* Wk = (const float*)d_in[3];
  const float* bk = (const float*)d_in[4];
  const float* Wv = (const float*)d_in[5];
  const float* bv = (const float*)d_in[6];
  const float* Wo = (const float*)d_in[7];
  const float* bo = (const float*)d_in[8];

  const size_t XN = (size_t)16384 * 768;
  const size_t WN = (size_t)768 * 768;

  u16* xb   = (u16*)d_ws;                  // [16384,768] bf16 (later aliased as concat)
  u16* wqkv = xb + XN;                     // [2304,768]
  u16* wo   = wqkv + 3 * WN;               // [768,768]
  float* bqkv = (float*)(wo + WN);         // [2304] fp32
  u16* qkv  = (u16*)(bqkv + 2304);         // [16384,2304]
  u16* vt   = qkv + (size_t)16384 * 2304;  // [192,64,1024] = vT[b][h][e][k]
  u16* cc   = xb;

  cvt_bf16<<<(int)(XN / 4 + 255) / 256, 256, 0, stream>>>(x, xb, (int)(XN / 4));
  cvt_bf16<<<(int)(WN / 4 + 255) / 256, 256, 0, stream>>>(Wq, wqkv, (int)(WN / 4));
  cvt_bf16<<<(int)(WN / 4 + 255) / 256, 256, 0, stream>>>(Wk, wqkv + WN, (int)(WN / 4));
  cvt_bf16<<<(int)(WN / 4 + 255) / 256, 256, 0, stream>>>(Wv, wqkv + 2 * WN, (int)(WN / 4));
  cvt_bf16<<<(int)(WN / 4 + 255) / 256, 256, 0, stream>>>(Wo, wo, (int)(WN / 4));
  hipMemcpyAsync(bqkv,        bq, 768 * sizeof(float), hipMemcpyDeviceToDevice, stream);
  hipMemcpyAsync(bqkv + 768,  bk, 768 * sizeof(float), hipMemcpyDeviceToDevice, stream);
  hipMemcpyAsync(bqkv + 1536, bv, 768 * sizeof(float), hipMemcpyDeviceToDevice, stream);

  gemm8<1, 1><<<576, 512, 0, stream>>>(xb, wqkv, bqkv, qkv, 2304, 768, 9);

  transpose_v<<<dim3(16, 12, 16), 256, 0, stream>>>(qkv, vt);

  attn_fwd<<<1536, 256, 0, stream>>>(qkv, vt, cc);

  gemm8<0, 0><<<192, 512, 0, stream>>>(cc, wo, bo, d_out, 768, 768, 3);
}